// Round 21
// baseline (1015.369 us; speedup 1.0000x reference)
//
#include <hip/hip_runtime.h>
#include <cmath>

#define BB   64
#define SEQ  1024
#define DD   256
#define HH   32
#define G4   128   // 4*H
#define VV   2048
#define RING 32    // h1 ring depth: L1 may run up to RING-1 steps ahead of L2

// fast sigmoid: e^x/(1+e^x) = 1 - 1/(1+e^x)
__device__ __forceinline__ float fsigm(float x) {
    return 1.0f - __builtin_amdgcn_rcpf(1.0f + __expf(x));
}
// fast tanh: 1 - 2/(1+e^(2x))
__device__ __forceinline__ float ftanh(float x) {
    return 1.0f - 2.0f * __builtin_amdgcn_rcpf(1.0f + __expf(2.0f * x));
}

// y[l] = x[l^32] via v_permlane32_swap (verified r10).
__device__ __forceinline__ float lane_xor32(float x, int half) {
#if __has_builtin(__builtin_amdgcn_permlane32_swap)
    auto r = __builtin_amdgcn_permlane32_swap(__float_as_uint(x), __float_as_uint(x),
                                              false, false);
    return __uint_as_float(half ? r[0] : r[1]);
#else
    return __shfl_xor(x, 32, 64);
#endif
}

#define FMA4F(A, W, H) \
    A = fmaf((W).w, (H).w, fmaf((W).z, (H).z, fmaf((W).y, (H).y, fmaf((W).x, (H).x, A))))

// ---- 32 named scalar weight floats (r18-proven pin path) -------------------
#define DECLW32(p) \
    float p##0,p##1,p##2,p##3,p##4,p##5,p##6,p##7, \
          p##8,p##9,p##10,p##11,p##12,p##13,p##14,p##15, \
          p##16,p##17,p##18,p##19,p##20,p##21,p##22,p##23, \
          p##24,p##25,p##26,p##27,p##28,p##29,p##30,p##31

#define LOADW32(p, base, row) do { \
    const float4* _q = (const float4*)&(base)[(row) * HH]; float4 _t; \
    _t=_q[0]; p##0 =_t.x; p##1 =_t.y; p##2 =_t.z; p##3 =_t.w; \
    _t=_q[1]; p##4 =_t.x; p##5 =_t.y; p##6 =_t.z; p##7 =_t.w; \
    _t=_q[2]; p##8 =_t.x; p##9 =_t.y; p##10=_t.z; p##11=_t.w; \
    _t=_q[3]; p##12=_t.x; p##13=_t.y; p##14=_t.z; p##15=_t.w; \
    _t=_q[4]; p##16=_t.x; p##17=_t.y; p##18=_t.z; p##19=_t.w; \
    _t=_q[5]; p##20=_t.x; p##21=_t.y; p##22=_t.z; p##23=_t.w; \
    _t=_q[6]; p##24=_t.x; p##25=_t.y; p##26=_t.z; p##27=_t.w; \
    _t=_q[7]; p##28=_t.x; p##29=_t.y; p##30=_t.z; p##31=_t.w; \
} while (0)

#define PIN32(p) do { \
    asm volatile("" : "+v"(p##0),"+v"(p##1),"+v"(p##2),"+v"(p##3), \
                      "+v"(p##4),"+v"(p##5),"+v"(p##6),"+v"(p##7)); \
    asm volatile("" : "+v"(p##8),"+v"(p##9),"+v"(p##10),"+v"(p##11), \
                      "+v"(p##12),"+v"(p##13),"+v"(p##14),"+v"(p##15)); \
    asm volatile("" : "+v"(p##16),"+v"(p##17),"+v"(p##18),"+v"(p##19), \
                      "+v"(p##20),"+v"(p##21),"+v"(p##22),"+v"(p##23)); \
    asm volatile("" : "+v"(p##24),"+v"(p##25),"+v"(p##26),"+v"(p##27), \
                      "+v"(p##28),"+v"(p##29),"+v"(p##30),"+v"(p##31)); \
} while (0)

#define DECLH8(h) float4 h##0, h##1, h##2, h##3, h##4, h##5, h##6, h##7
#define LOADH(h, src) do { \
    h##0=(src)[0]; h##1=(src)[1]; h##2=(src)[2]; h##3=(src)[3]; \
    h##4=(src)[4]; h##5=(src)[5]; h##6=(src)[6]; h##7=(src)[7]; \
} while (0)

// 32-long dot, scalar weights x float4 h-quads (chain grouping == r16 bitwise)
#define DOT32S(res, P, Q) do { \
    float _a0=0.f,_a1=0.f,_a2=0.f,_a3=0.f; \
    _a0=fmaf(P##3 ,(Q##0).w,fmaf(P##2 ,(Q##0).z,fmaf(P##1 ,(Q##0).y,fmaf(P##0 ,(Q##0).x,_a0)))); \
    _a1=fmaf(P##7 ,(Q##1).w,fmaf(P##6 ,(Q##1).z,fmaf(P##5 ,(Q##1).y,fmaf(P##4 ,(Q##1).x,_a1)))); \
    _a2=fmaf(P##11,(Q##2).w,fmaf(P##10,(Q##2).z,fmaf(P##9 ,(Q##2).y,fmaf(P##8 ,(Q##2).x,_a2)))); \
    _a3=fmaf(P##15,(Q##3).w,fmaf(P##14,(Q##3).z,fmaf(P##13,(Q##3).y,fmaf(P##12,(Q##3).x,_a3)))); \
    _a0=fmaf(P##19,(Q##4).w,fmaf(P##18,(Q##4).z,fmaf(P##17,(Q##4).y,fmaf(P##16,(Q##4).x,_a0)))); \
    _a1=fmaf(P##23,(Q##5).w,fmaf(P##22,(Q##5).z,fmaf(P##21,(Q##5).y,fmaf(P##20,(Q##5).x,_a1)))); \
    _a2=fmaf(P##27,(Q##6).w,fmaf(P##26,(Q##6).z,fmaf(P##25,(Q##6).y,fmaf(P##24,(Q##6).x,_a2)))); \
    _a3=fmaf(P##31,(Q##7).w,fmaf(P##30,(Q##7).z,fmaf(P##29,(Q##7).y,fmaf(P##28,(Q##7).x,_a3)))); \
    res=(_a0+_a1)+(_a2+_a3); \
} while (0)

// ---------------------------------------------------------------------------
// Kernel A1 (r20-proven): 8 vocab rows/block; W_ih1 quad loaded once per block
// ---------------------------------------------------------------------------
__global__ __launch_bounds__(128) void emb_proj_kernel(
    const float* __restrict__ emb, const float* __restrict__ W_ih1,
    const float* __restrict__ b_ih1, const float* __restrict__ b_hh1,
    float* __restrict__ emb_proj)
{
    const int v0 = blockIdx.x * 8;
    const int j = threadIdx.x;
    __shared__ __align__(16) float ev[8][DD];

    {
        const float4* esrc = (const float4*)&emb[(long)v0 * DD];
        float4* edst = (float4*)ev;
#pragma unroll
        for (int i = 0; i < 4; ++i) edst[j + 128 * i] = esrc[j + 128 * i];
    }
    __syncthreads();

    const float bias = b_ih1[j] + b_hh1[j];
    float acc[8];
#pragma unroll
    for (int v = 0; v < 8; ++v) acc[v] = bias;

    const float4* wrow = (const float4*)&W_ih1[j * DD];
#pragma unroll 4
    for (int q = 0; q < DD / 4; ++q) {
        const float4 w = wrow[q];
#pragma unroll
        for (int v = 0; v < 8; ++v) {
            const float4 e = ((const float4*)ev[v])[q];
            acc[v] += w.x * e.x + w.y * e.y + w.z * e.z + w.w * e.w;
        }
    }
#pragma unroll
    for (int v = 0; v < 8; ++v)
        emb_proj[(v0 + v) * G4 + j] = acc[v];
}

// ---------------------------------------------------------------------------
// Kernel A2: W_fcT[k][v] = W_fc[v][k]
// ---------------------------------------------------------------------------
__global__ __launch_bounds__(256) void transpose_wfc_kernel(
    const float* __restrict__ W_fc, float* __restrict__ W_fcT)
{
    int i = blockIdx.x * 256 + threadIdx.x;
    int v = i >> 5;
    int k = i & 31;
    W_fcT[k * VV + v] = W_fc[i];
}

// ---------------------------------------------------------------------------
// Kernel B: 2-wave producer-consumer LSTM + amdgpu_waves_per_eu(1,1).
// r19 (this exact kernel, verified correct) failed ONLY because the allocator
// granted 64 VGPRs -> the 64 pinned weight floats per wave spilled to scratch
// and reloaded per step with fully exposed latency (no co-resident waves to
// hide it). r20 proved waves_per_eu(1,1) raises the grant (76->132). With
// weights resident, step = max(L1 span, L2 span) with NO barrier in the loop.
// ---------------------------------------------------------------------------
__global__ __launch_bounds__(128)
__attribute__((amdgpu_waves_per_eu(1, 1)))
void lstm_rec_pc_kernel(
    const int* __restrict__ x_ids, const float* __restrict__ emb_proj,
    const float* __restrict__ W_hh1, const float* __restrict__ W_ih2,
    const float* __restrict__ W_hh2, const float* __restrict__ b_ih2,
    const float* __restrict__ b_hh2, float* __restrict__ h2_all)
{
    const int tid = threadIdx.x;
    const int b   = blockIdx.x;
    const int wid = tid >> 6;          // 0 = layer1, 1 = layer2
    const int l   = tid & 63;
    const int half = l >> 5;
    const int r0 = l;
    const int r1 = l + 64;

    // r0 rows (i or f): sigmoid. r1 rows: g (tanh) on half0, o (sigm) on half1.
    const float a1  = half ? 1.0f : 2.0f;
    const float c1p = half ? 1.0f : 2.0f;

    __shared__ __align__(16) float4 T3[8 * 128];      // W_hh2 quad-transposed (16KB)
    __shared__ __align__(16) float h1ring[RING][HH];  // h1(t) at slot t&(RING-1)
    __shared__ __align__(16) float h2buf[2][HH];      // h2(s) at slot s&1
    __shared__ int flags[2];                          // [0]=l1_done, [1]=l2_done
    volatile int* vfl = flags;

    // stage W_hh2: T3[q*128+row] = W_hh2[row][4q..4q+3]
    {
        const float4* s3 = (const float4*)W_hh2;
        for (int i = tid; i < 1024; i += 128) {
            const int q = i >> 7, rr = i & 127;
            T3[i] = s3[rr * 8 + q];
        }
    }
    if (tid == 0) { flags[0] = 0; flags[1] = 0; }
    if (tid < HH) { h1ring[RING - 1][tid] = 0.0f; h2buf[1][tid] = 0.0f; }
    __syncthreads();   // once, before the loop

    if (wid == 0) {
        // ================= layer 1 wave =================
        DECLW32(w); DECLW32(x);
        LOADW32(w, W_hh1, r0);
        LOADW32(x, W_hh1, r1);
        PIN32(w); PIN32(x);

        const int* ids = x_ids + b * SEQ;
        int idn = ids[1];
        float ep0 = emb_proj[ids[0] * G4 + r0];
        float ep1 = emb_proj[ids[0] * G4 + r1];
        float c1 = 0.0f;
        int l2cache = 0;

        for (int t = 0; t < SEQ; ++t) {
            const float ep0n = emb_proj[idn * G4 + r0];
            const float ep1n = emb_proj[idn * G4 + r1];
            const int tn2 = (t + 2 < SEQ) ? (t + 2) : (SEQ - 1);
            const int idn2 = ids[tn2];

            // dot: W_hh1 rows r0,r1 (PINNED regs) . h1(t-1)
            DECLH8(h1q);
            LOADH(h1q, (const float4*)h1ring[(t + RING - 1) & (RING - 1)]);
            float d0, d1;
            DOT32S(d0, w, h1q);
            DOT32S(d1, x, h1q);
            const float gr0 = ep0 + d0;
            const float gr1 = ep1 + d1;

            const float A0 = fsigm(gr0);
            const float A1 = 1.0f - c1p * __builtin_amdgcn_rcpf(1.0f + __expf(a1 * gr1));
            const float B0 = lane_xor32(A0, half);
            const float B1 = lane_xor32(A1, half);
            const float gi = half ? B0 : A0;
            const float gf = half ? A0 : B0;
            const float gg = half ? B1 : A1;
            const float go = half ? A1 : B1;

            c1 = gf * c1 + gi * gg;
            const float h1n = go * ftanh(c1);

            // ring-slot guard (rare: only if L2 falls > RING-1 behind)
            if (t >= RING) {
                const int need = t - (RING - 1);
                while (l2cache < need) {
                    l2cache = vfl[1];
                    if (l2cache >= need) break;
                    __builtin_amdgcn_s_sleep(1);
                }
            }
            asm volatile("" ::: "memory");
            if (l < HH) h1ring[t & (RING - 1)][l] = h1n;
            asm volatile("s_waitcnt lgkmcnt(0)" ::: "memory");
            if (l == 0) vfl[0] = t + 1;

            ep0 = ep0n; ep1 = ep1n; idn = idn2;
        }
    } else {
        // ================= layer 2 wave =================
        DECLW32(ew); DECLW32(fx);
        LOADW32(ew, W_ih2, r0);
        LOADW32(fx, W_ih2, r1);
        PIN32(ew); PIN32(fx);

        const float bias20 = b_ih2[r0] + b_hh2[r0];
        const float bias21 = b_ih2[r1] + b_hh2[r1];
        float c2 = 0.0f;
        float* h2out = h2_all + (long)b * SEQ * HH;
        int l1cache = 0;

        for (int s = 0; s < SEQ; ++s) {
            // wait for h1(s): one poll covers many future steps (cached)
            const int need = s + 1;
            while (l1cache < need) {
                l1cache = vfl[0];
                if (l1cache >= need) break;
                __builtin_amdgcn_s_sleep(1);
            }
            asm volatile("" ::: "memory");

            DECLH8(h1q); DECLH8(h2q);
            LOADH(h1q, (const float4*)h1ring[s & (RING - 1)]);
            LOADH(h2q, (const float4*)h2buf[(s + 1) & 1]);

            // e = W_ih2 rows (PINNED regs) . h1(s)
            float e0, e1;
            DOT32S(e0, ew, h1q);
            DOT32S(e1, fx, h1q);

            // p = W_hh2 rows (LDS T3) . h2(s-1)   (r18 chain grouping)
            float pa0=0.f,pa1=0.f,pa2=0.f,pa3=0.f, pb0=0.f,pb1=0.f,pb2=0.f,pb3=0.f;
            float4 wq, xq;
            wq=T3[0*128+r0]; xq=T3[0*128+r1]; FMA4F(pa0,wq,h2q0); FMA4F(pb0,xq,h2q0);
            wq=T3[1*128+r0]; xq=T3[1*128+r1]; FMA4F(pa1,wq,h2q1); FMA4F(pb1,xq,h2q1);
            wq=T3[2*128+r0]; xq=T3[2*128+r1]; FMA4F(pa2,wq,h2q2); FMA4F(pb2,xq,h2q2);
            wq=T3[3*128+r0]; xq=T3[3*128+r1]; FMA4F(pa3,wq,h2q3); FMA4F(pb3,xq,h2q3);
            wq=T3[4*128+r0]; xq=T3[4*128+r1]; FMA4F(pa0,wq,h2q4); FMA4F(pb0,xq,h2q4);
            wq=T3[5*128+r0]; xq=T3[5*128+r1]; FMA4F(pa1,wq,h2q5); FMA4F(pb1,xq,h2q5);
            wq=T3[6*128+r0]; xq=T3[6*128+r1]; FMA4F(pa2,wq,h2q6); FMA4F(pb2,xq,h2q6);
            wq=T3[7*128+r0]; xq=T3[7*128+r1]; FMA4F(pa3,wq,h2q7); FMA4F(pb3,xq,h2q7);
            const float p0 = (pa0 + pa1) + (pa2 + pa3);
            const float p1 = (pb0 + pb1) + (pb2 + pb3);
            const float qr0 = bias20 + p0 + e0;
            const float qr1 = bias21 + p1 + e1;

            const float C0 = fsigm(qr0);
            const float C1 = 1.0f - c1p * __builtin_amdgcn_rcpf(1.0f + __expf(a1 * qr1));
            const float D0 = lane_xor32(C0, half);
            const float D1 = lane_xor32(C1, half);
            const float pi = half ? D0 : C0;
            const float pf = half ? C0 : D0;
            const float pg = half ? D1 : C1;
            const float po = half ? C1 : D1;

            c2 = pf * c2 + pi * pg;
            const float h2n = po * ftanh(c2);

            if (l < HH) {
                h2buf[s & 1][l] = h2n;
                h2out[(long)s * HH + l] = h2n;
            }
            asm volatile("s_waitcnt lgkmcnt(0)" ::: "memory");
            if (l == 0) vfl[1] = s + 1;
        }
    }
}

// ---------------------------------------------------------------------------
// Kernel C: logits = h2 @ W_fc^T + b_fc, row softmax, write [B*S][V].
// r1/r11-proven config: 8 rows/block, 256 threads, 8 vocab cols/thread.
// ---------------------------------------------------------------------------
__global__ __launch_bounds__(256) void fc_softmax_kernel(
    const float* __restrict__ h2_all, const float* __restrict__ W_fcT,
    const float* __restrict__ b_fc, float* __restrict__ out)
{
    const int tid = threadIdx.x;
    const long rowbase = (long)blockIdx.x * 8;
    __shared__ __align__(16) float h2t[8][HH];
    __shared__ float wred[8][4];

    h2t[tid >> 5][tid & 31] = h2_all[rowbase * HH + tid];
    __syncthreads();

    const int v0 = tid * 8;
    const float4 bf0 = *(const float4*)&b_fc[v0];
    const float4 bf1 = *(const float4*)&b_fc[v0 + 4];
    float acc[8][8];
#pragma unroll
    for (int r = 0; r < 8; ++r) {
        acc[r][0] = bf0.x; acc[r][1] = bf0.y; acc[r][2] = bf0.z; acc[r][3] = bf0.w;
        acc[r][4] = bf1.x; acc[r][5] = bf1.y; acc[r][6] = bf1.z; acc[r][7] = bf1.w;
    }

#pragma unroll
    for (int kq = 0; kq < 8; ++kq) {
        const int k = kq * 4;
        float4 wa[4], wb[4];
#pragma unroll
        for (int i = 0; i < 4; ++i) {
            wa[i] = *(const float4*)&W_fcT[(k + i) * VV + v0];
            wb[i] = *(const float4*)&W_fcT[(k + i) * VV + v0 + 4];
        }
#pragma unroll
        for (int r = 0; r < 8; ++r) {
            const float4 h = *(const float4*)&h2t[r][k];
            const float hh[4] = {h.x, h.y, h.z, h.w};
#pragma unroll
            for (int i = 0; i < 4; ++i) {
                acc[r][0] += hh[i] * wa[i].x; acc[r][1] += hh[i] * wa[i].y;
                acc[r][2] += hh[i] * wa[i].z; acc[r][3] += hh[i] * wa[i].w;
                acc[r][4] += hh[i] * wb[i].x; acc[r][5] += hh[i] * wb[i].y;
                acc[r][6] += hh[i] * wb[i].z; acc[r][7] += hh[i] * wb[i].w;
            }
        }
    }

    const int wv = tid >> 6;
    const int lane = tid & 63;

    float m[8];
#pragma unroll
    for (int r = 0; r < 8; ++r) {
        float v = acc[r][0];
#pragma unroll
        for (int c = 1; c < 8; ++c) v = fmaxf(v, acc[r][c]);
#pragma unroll
        for (int s = 32; s >= 1; s >>= 1) v = fmaxf(v, __shfl_xor(v, s, 64));
        m[r] = v;
    }
    if (lane == 0) {
#pragma unroll
        for (int r = 0; r < 8; ++r) wred[r][wv] = m[r];
    }
    __syncthreads();
    float rm[8];
#pragma unroll
    for (int r = 0; r < 8; ++r)
        rm[r] = fmaxf(fmaxf(wred[r][0], wred[r][1]), fmaxf(wred[r][2], wred[r][3]));
    __syncthreads();

    float s[8];
#pragma unroll
    for (int r = 0; r < 8; ++r) {
        float sum = 0.0f;
#pragma unroll
        for (int c = 0; c < 8; ++c) {
            float e = __expf(acc[r][c] - rm[r]);
            acc[r][c] = e;
            sum += e;
        }
#pragma unroll
        for (int st = 32; st >= 1; st >>= 1) sum += __shfl_xor(sum, st, 64);
        s[r] = sum;
    }
    if (lane == 0) {
#pragma unroll
        for (int r = 0; r < 8; ++r) wred[r][wv] = s[r];
    }
    __syncthreads();

#pragma unroll
    for (int r = 0; r < 8; ++r) {
        const float rs = wred[r][0] + wred[r][1] + wred[r][2] + wred[r][3];
        const float inv = 1.0f / rs;
        float4 o0 = make_float4(acc[r][0] * inv, acc[r][1] * inv, acc[r][2] * inv, acc[r][3] * inv);
        float4 o1 = make_float4(acc[r][4] * inv, acc[r][5] * inv, acc[r][6] * inv, acc[r][7] * inv);
        float* op = out + (rowbase + r) * VV + v0;
        *(float4*)op = o0;
        *(float4*)(op + 4) = o1;
    }
}

// ---------------------------------------------------------------------------
extern "C" void kernel_launch(void* const* d_in, const int* in_sizes, int n_in,
                              void* d_out, int out_size, void* d_ws, size_t ws_size,
                              hipStream_t stream)
{
    const int*   x_ids = (const int*)d_in[0];
    const float* emb   = (const float*)d_in[1];
    const float* W_ih1 = (const float*)d_in[2];
    const float* W_hh1 = (const float*)d_in[3];
    const float* b_ih1 = (const float*)d_in[4];
    const float* b_hh1 = (const float*)d_in[5];
    const float* W_ih2 = (const float*)d_in[6];
    const float* W_hh2 = (const float*)d_in[7];
    const float* b_ih2 = (const float*)d_in[8];
    const float* b_hh2 = (const float*)d_in[9];
    const float* W_fc  = (const float*)d_in[10];
    const float* b_fc  = (const float*)d_in[11];
    float* out = (float*)d_out;

    float* ws = (float*)d_ws;
    float* emb_proj = ws;                         // V*4H   = 262144
    float* W_fcT    = ws + 262144;                // H*V    = 65536
    float* h2_all   = ws + 262144 + 65536;        // B*S*H  = 2097152

    emb_proj_kernel<<<VV / 8, 128, 0, stream>>>(emb, W_ih1, b_ih1, b_hh1, emb_proj);
    transpose_wfc_kernel<<<(VV * HH) / 256, 256, 0, stream>>>(W_fc, W_fcT);
    lstm_rec_pc_kernel<<<BB, 128, 0, stream>>>(x_ids, emb_proj, W_hh1, W_ih2, W_hh2,
                                               b_ih2, b_hh2, h2_all);
    fc_softmax_kernel<<<(BB * SEQ) / 8, 256, 0, stream>>>(h2_all, W_fcT, b_fc, out);
}

// Round 22
// 695.730 us; speedup vs baseline: 1.4594x; 1.4594x over previous
//
#include <hip/hip_runtime.h>
#include <cmath>

#define BB   64
#define SEQ  1024
#define DD   256
#define HH   32
#define G4   128   // 4*H
#define VV   2048

// fast tanh: 1 - 2/(1+e^(2x))
__device__ __forceinline__ float ftanh(float x) {
    return 1.0f - 2.0f * __builtin_amdgcn_rcpf(1.0f + __expf(2.0f * x));
}

// y[l] = x[l^32] via v_permlane32_swap (verified r10/r14).
__device__ __forceinline__ float lane_xor32(float x, int half) {
#if __has_builtin(__builtin_amdgcn_permlane32_swap)
    auto r = __builtin_amdgcn_permlane32_swap(__float_as_uint(x), __float_as_uint(x),
                                              false, false);
    return __uint_as_float(half ? r[0] : r[1]);
#else
    return __shfl_xor(x, 32, 64);
#endif
}

// y[l] = x[l^16] via v_permlane16_swap (verified r14: bit-exact absmax).
__device__ __forceinline__ float lane_xor16(float x, int l) {
#if __has_builtin(__builtin_amdgcn_permlane16_swap)
    auto r = __builtin_amdgcn_permlane16_swap(__float_as_uint(x), __float_as_uint(x),
                                              false, false);
    return __uint_as_float((l & 16) ? r[0] : r[1]);
#else
    return __shfl_xor(x, 16, 64);
#endif
}

// LDS-only barrier (r14-verified): don't drain vmcnt, so the per-step h2
// global store and ep prefetch loads stay in flight across steps.
__device__ __forceinline__ void lds_barrier() {
    asm volatile("s_waitcnt lgkmcnt(0)" ::: "memory");
    __builtin_amdgcn_s_barrier();
}

#define FMA4F(A, W, H) \
    A = fmaf((W).w, (H).w, fmaf((W).z, (H).z, fmaf((W).y, (H).y, fmaf((W).x, (H).x, A))))

// ---------------------------------------------------------------------------
// Kernel A1 (r20-proven): 8 vocab rows/block; W_ih1 quad loaded once per block
// ---------------------------------------------------------------------------
__global__ __launch_bounds__(128) void emb_proj_kernel(
    const float* __restrict__ emb, const float* __restrict__ W_ih1,
    const float* __restrict__ b_ih1, const float* __restrict__ b_hh1,
    float* __restrict__ emb_proj)
{
    const int v0 = blockIdx.x * 8;
    const int j = threadIdx.x;
    __shared__ __align__(16) float ev[8][DD];

    {
        const float4* esrc = (const float4*)&emb[(long)v0 * DD];
        float4* edst = (float4*)ev;
#pragma unroll
        for (int i = 0; i < 4; ++i) edst[j + 128 * i] = esrc[j + 128 * i];
    }
    __syncthreads();

    const float bias = b_ih1[j] + b_hh1[j];
    float acc[8];
#pragma unroll
    for (int v = 0; v < 8; ++v) acc[v] = bias;

    const float4* wrow = (const float4*)&W_ih1[j * DD];
#pragma unroll 4
    for (int q = 0; q < DD / 4; ++q) {
        const float4 w = wrow[q];
#pragma unroll
        for (int v = 0; v < 8; ++v) {
            const float4 e = ((const float4*)ev[v])[q];
            acc[v] += w.x * e.x + w.y * e.y + w.z * e.z + w.w * e.w;
        }
    }
#pragma unroll
    for (int v = 0; v < 8; ++v)
        emb_proj[(v0 + v) * G4 + j] = acc[v];
}

// ---------------------------------------------------------------------------
// Kernel A2: W_fcT[k][v] = W_fc[v][k]
// ---------------------------------------------------------------------------
__global__ __launch_bounds__(256) void transpose_wfc_kernel(
    const float* __restrict__ W_fc, float* __restrict__ W_fcT)
{
    int i = blockIdx.x * 256 + threadIdx.x;
    int v = i >> 5;
    int k = i & 31;
    W_fcT[k * VV + v] = W_fc[i];
}

// ---------------------------------------------------------------------------
// Kernel B (r20-proven BEST, unchanged): r14 4-wave pipelined LSTM +
// amdgpu_waves_per_eu(1,1). waves 0,1: layer1 step t; waves 2,3: layer2 t-1.
// ---------------------------------------------------------------------------
__global__ __launch_bounds__(256)
__attribute__((amdgpu_waves_per_eu(1, 1)))
void lstm_rec_pipe_kernel(
    const int* __restrict__ x_ids, const float* __restrict__ emb_proj,
    const float* __restrict__ W_hh1, const float* __restrict__ W_ih2,
    const float* __restrict__ W_hh2, const float* __restrict__ b_ih2,
    const float* __restrict__ b_hh2, float* __restrict__ h2_all)
{
    const int tid = threadIdx.x;
    const int b   = blockIdx.x;
    const int wid = tid >> 6;          // 0,1 -> layer1; 2,3 -> layer2
    const int l   = tid & 63;
    const int g   = (l >> 4) & 3;      // gate index
    const int half = l >> 5;
    const int u   = (l & 15) + 16 * (wid & 1);
    const int row = g * 32 + u;

    const float aa = (g == 2) ? 2.0f : 1.0f;   // act: 1 - kk*rcp(1+exp(aa*x))
    const float kk = (g == 2) ? 2.0f : 1.0f;
    const bool is_l1 = (wid < 2);
    const int  gbit0 = g & 1, gbit1 = g >> 1;

    // weights: L1 waves -> w=W_hh1[row]; L2 waves -> w=W_ih2[row], v=W_hh2[row]
    float4 w0,w1,w2,w3,w4,w5,w6,w7, v0,v1,v2,v3,v4,v5,v6,v7;
    {
        const float* wsrc = is_l1 ? W_hh1 : W_ih2;
        const float4* pw = (const float4*)&wsrc[row * HH];
        w0=pw[0]; w1=pw[1]; w2=pw[2]; w3=pw[3];
        w4=pw[4]; w5=pw[5]; w6=pw[6]; w7=pw[7];
        const float4* pv = (const float4*)&W_hh2[row * HH];
        v0=pv[0]; v1=pv[1]; v2=pv[2]; v3=pv[3];
        v4=pv[4]; v5=pv[5]; v6=pv[6]; v7=pv[7];
    }
    const float bias2 = b_ih2[row] + b_hh2[row];

    __shared__ __align__(16) float h1s[2][HH];
    __shared__ __align__(16) float h2s[2][HH];
    if (tid < 64) { h1s[tid >> 5][tid & 31] = 0.0f; h2s[tid >> 5][tid & 31] = 0.0f; }
    __syncthreads();

    float cst = 0.0f;                  // c1 (L1 waves) or c2 (L2 waves)
    const int* ids = x_ids + b * SEQ;
    float ep = 0.0f; int idn = 0;
    if (is_l1) {
        ep  = emb_proj[ids[0] * G4 + row];
        idn = ids[1];
    }
    float* h2out = h2_all + (long)b * SEQ * HH;

    for (int t = 0; t <= SEQ; ++t) {
        const int cur = t & 1, nxt = cur ^ 1;
        if (is_l1) {
            if (t < SEQ) {
                // prefetch ep(t+1) — stays in flight across the counted barrier
                const float epn = emb_proj[idn * G4 + row];
                const int tn2 = (t + 2 < SEQ) ? (t + 2) : (SEQ - 1);
                const int idn2 = ids[tn2];

                // dot: W_hh1[row] . h1(t-1)
                const float4* hv = (const float4*)h1s[cur];
                float a0=0.f, a1=0.f, a2=0.f, a3=0.f;
                float4 q;
                q=hv[0]; FMA4F(a0,w0,q);  q=hv[1]; FMA4F(a1,w1,q);
                q=hv[2]; FMA4F(a2,w2,q);  q=hv[3]; FMA4F(a3,w3,q);
                q=hv[4]; FMA4F(a0,w4,q);  q=hv[5]; FMA4F(a1,w5,q);
                q=hv[6]; FMA4F(a2,w6,q);  q=hv[7]; FMA4F(a3,w7,q);
                const float pre = ep + ((a0 + a1) + (a2 + a3));

                const float A = 1.0f - kk * __builtin_amdgcn_rcpf(1.0f + __expf(aa * pre));
                const float B = lane_xor16(A, l);        // gate g^1
                const float C = lane_xor32(A, half);     // gate g^2
                const float D = lane_xor32(B, half);     // gate g^3
                const float gi = gbit1 ? (gbit0 ? D : C) : (gbit0 ? B : A);
                const float gf = gbit1 ? (gbit0 ? C : D) : (gbit0 ? A : B);
                const float gt = gbit1 ? (gbit0 ? B : A) : (gbit0 ? D : C);
                const float go = gbit1 ? (gbit0 ? A : B) : (gbit0 ? C : D);

                cst = gf * cst + gi * gt;
                const float hn = go * ftanh(cst);
                if (g == 0) h1s[nxt][u] = hn;

                ep = epn; idn = idn2;
            }
        } else {
            if (t >= 1) {
                const int s = t - 1;
                // dots: W_ih2[row].h1(s) and W_hh2[row].h2(s-1)
                const float4* h1v = (const float4*)h1s[cur];
                const float4* h2v = (const float4*)h2s[cur];
                float e0=0.f, e1=0.f, e2=0.f, e3=0.f;
                float p0=0.f, p1=0.f, p2=0.f, p3=0.f;
                float4 q;
                q=h1v[0]; FMA4F(e0,w0,q);  q=h1v[1]; FMA4F(e1,w1,q);
                q=h1v[2]; FMA4F(e2,w2,q);  q=h1v[3]; FMA4F(e3,w3,q);
                q=h1v[4]; FMA4F(e0,w4,q);  q=h1v[5]; FMA4F(e1,w5,q);
                q=h1v[6]; FMA4F(e2,w6,q);  q=h1v[7]; FMA4F(e3,w7,q);
                q=h2v[0]; FMA4F(p0,v0,q);  q=h2v[1]; FMA4F(p1,v1,q);
                q=h2v[2]; FMA4F(p2,v2,q);  q=h2v[3]; FMA4F(p3,v3,q);
                q=h2v[4]; FMA4F(p0,v4,q);  q=h2v[5]; FMA4F(p1,v5,q);
                q=h2v[6]; FMA4F(p2,v6,q);  q=h2v[7]; FMA4F(p3,v7,q);
                const float esum = (e0 + e1) + (e2 + e3);
                const float psum = (p0 + p1) + (p2 + p3);
                const float pre = bias2 + psum + esum;

                const float A = 1.0f - kk * __builtin_amdgcn_rcpf(1.0f + __expf(aa * pre));
                const float B = lane_xor16(A, l);
                const float C = lane_xor32(A, half);
                const float D = lane_xor32(B, half);
                const float gi = gbit1 ? (gbit0 ? D : C) : (gbit0 ? B : A);
                const float gf = gbit1 ? (gbit0 ? C : D) : (gbit0 ? A : B);
                const float gt = gbit1 ? (gbit0 ? B : A) : (gbit0 ? D : C);
                const float go = gbit1 ? (gbit0 ? A : B) : (gbit0 ? C : D);

                cst = gf * cst + gi * gt;
                const float hn = go * ftanh(cst);
                if (g == 0) {
                    h2s[nxt][u] = hn;
                    h2out[(long)s * HH + u] = hn;   // store floats across barrier
                }
            }
        }
        lds_barrier();
    }
}

// ---------------------------------------------------------------------------
// Kernel C: logits = h2 @ W_fc^T + b_fc, row softmax, write [B*S][V].
// r22: 16 rows/block x 512 threads x 4 cols/thread. Halves W_fcT L2 traffic
// (2GB -> 1GB) vs the 8-row config while keeping acc at only [16][4]=64
// VGPRs (r2's failed 16-row used 128 acc regs at 256 thr). Per-element
// accumulation order identical -> bitwise-same output.
// ---------------------------------------------------------------------------
__global__ __launch_bounds__(512) void fc_softmax_kernel(
    const float* __restrict__ h2_all, const float* __restrict__ W_fcT,
    const float* __restrict__ b_fc, float* __restrict__ out)
{
    const int tid = threadIdx.x;
    const long rowbase = (long)blockIdx.x * 16;
    __shared__ __align__(16) float h2t[16][HH];
    __shared__ float wred[16][8];

    h2t[tid >> 5][tid & 31] = h2_all[rowbase * HH + tid];
    __syncthreads();

    const int v0 = tid * 4;
    const float4 bf = *(const float4*)&b_fc[v0];
    float acc[16][4];
#pragma unroll
    for (int r = 0; r < 16; ++r) {
        acc[r][0] = bf.x; acc[r][1] = bf.y; acc[r][2] = bf.z; acc[r][3] = bf.w;
    }

#pragma unroll
    for (int kq = 0; kq < 8; ++kq) {
        const int k = kq * 4;
        float4 wa[4];
#pragma unroll
        for (int i = 0; i < 4; ++i)
            wa[i] = *(const float4*)&W_fcT[(k + i) * VV + v0];
#pragma unroll
        for (int r = 0; r < 16; ++r) {
            const float4 h = *(const float4*)&h2t[r][k];
            const float hh[4] = {h.x, h.y, h.z, h.w};
#pragma unroll
            for (int i = 0; i < 4; ++i) {
                acc[r][0] += hh[i] * wa[i].x;
                acc[r][1] += hh[i] * wa[i].y;
                acc[r][2] += hh[i] * wa[i].z;
                acc[r][3] += hh[i] * wa[i].w;
            }
        }
    }

    const int wv = tid >> 6;     // wave id 0..7
    const int lane = tid & 63;

    // ---- row max (block-wide over 8 waves) ----
    float m[16];
#pragma unroll
    for (int r = 0; r < 16; ++r) {
        float v = fmaxf(fmaxf(acc[r][0], acc[r][1]), fmaxf(acc[r][2], acc[r][3]));
#pragma unroll
        for (int s = 32; s >= 1; s >>= 1) v = fmaxf(v, __shfl_xor(v, s, 64));
        m[r] = v;
    }
    if (lane == 0) {
#pragma unroll
        for (int r = 0; r < 16; ++r) wred[r][wv] = m[r];
    }
    __syncthreads();
    float rm[16];
#pragma unroll
    for (int r = 0; r < 16; ++r) {
        const float* wr = wred[r];
        rm[r] = fmaxf(fmaxf(fmaxf(wr[0], wr[1]), fmaxf(wr[2], wr[3])),
                      fmaxf(fmaxf(wr[4], wr[5]), fmaxf(wr[6], wr[7])));
    }
    __syncthreads();

    // ---- exp + row sum ----
    float s[16];
#pragma unroll
    for (int r = 0; r < 16; ++r) {
        float sum = 0.0f;
#pragma unroll
        for (int c = 0; c < 4; ++c) {
            float e = __expf(acc[r][c] - rm[r]);
            acc[r][c] = e;
            sum += e;
        }
#pragma unroll
        for (int st = 32; st >= 1; st >>= 1) sum += __shfl_xor(sum, st, 64);
        s[r] = sum;
    }
    if (lane == 0) {
#pragma unroll
        for (int r = 0; r < 16; ++r) wred[r][wv] = s[r];
    }
    __syncthreads();

#pragma unroll
    for (int r = 0; r < 16; ++r) {
        const float* wr = wred[r];
        const float rs = ((wr[0] + wr[1]) + (wr[2] + wr[3]))
                       + ((wr[4] + wr[5]) + (wr[6] + wr[7]));
        const float inv = 1.0f / rs;
        float4 o = make_float4(acc[r][0] * inv, acc[r][1] * inv,
                               acc[r][2] * inv, acc[r][3] * inv);
        *(float4*)(out + (rowbase + r) * VV + v0) = o;
    }
}

// ---------------------------------------------------------------------------
extern "C" void kernel_launch(void* const* d_in, const int* in_sizes, int n_in,
                              void* d_out, int out_size, void* d_ws, size_t ws_size,
                              hipStream_t stream)
{
    const int*   x_ids = (const int*)d_in[0];
    const float* emb   = (const float*)d_in[1];
    const float* W_ih1 = (const float*)d_in[2];
    const float* W_hh1 = (const float*)d_in[3];
    const float* b_ih1 = (const float*)d_in[4];
    const float* b_hh1 = (const float*)d_in[5];
    const float* W_ih2 = (const float*)d_in[6];
    const float* W_hh2 = (const float*)d_in[7];
    const float* b_ih2 = (const float*)d_in[8];
    const float* b_hh2 = (const float*)d_in[9];
    const float* W_fc  = (const float*)d_in[10];
    const float* b_fc  = (const float*)d_in[11];
    float* out = (float*)d_out;

    float* ws = (float*)d_ws;
    float* emb_proj = ws;                         // V*4H   = 262144
    float* W_fcT    = ws + 262144;                // H*V    = 65536
    float* h2_all   = ws + 262144 + 65536;        // B*S*H  = 2097152

    emb_proj_kernel<<<VV / 8, 128, 0, stream>>>(emb, W_ih1, b_ih1, b_hh1, emb_proj);
    transpose_wfc_kernel<<<(VV * HH) / 256, 256, 0, stream>>>(W_fc, W_fcT);
    lstm_rec_pipe_kernel<<<BB, 256, 0, stream>>>(x_ids, emb_proj, W_hh1, W_ih2, W_hh2,
                                                 b_ih2, b_hh2, h2_all);
    fc_softmax_kernel<<<(BB * SEQ) / 16, 512, 0, stream>>>(h2_all, W_fcT, b_fc, out);
}

// Round 23
// 675.890 us; speedup vs baseline: 1.5023x; 1.0294x over previous
//
#include <hip/hip_runtime.h>
#include <cmath>

#define BB   64
#define SEQ  1024
#define DD   256
#define HH   32
#define G4   128   // 4*H
#define VV   2048

// fast tanh: 1 - 2/(1+e^(2x))
__device__ __forceinline__ float ftanh(float x) {
    return 1.0f - 2.0f * __builtin_amdgcn_rcpf(1.0f + __expf(2.0f * x));
}

// y[l] = x[l^32] via v_permlane32_swap (verified r10/r14).
__device__ __forceinline__ float lane_xor32(float x, int half) {
#if __has_builtin(__builtin_amdgcn_permlane32_swap)
    auto r = __builtin_amdgcn_permlane32_swap(__float_as_uint(x), __float_as_uint(x),
                                              false, false);
    return __uint_as_float(half ? r[0] : r[1]);
#else
    return __shfl_xor(x, 32, 64);
#endif
}

// y[l] = x[l^16] via v_permlane16_swap (verified r14: bit-exact absmax).
__device__ __forceinline__ float lane_xor16(float x, int l) {
#if __has_builtin(__builtin_amdgcn_permlane16_swap)
    auto r = __builtin_amdgcn_permlane16_swap(__float_as_uint(x), __float_as_uint(x),
                                              false, false);
    return __uint_as_float((l & 16) ? r[0] : r[1]);
#else
    return __shfl_xor(x, 16, 64);
#endif
}

// LDS-only barrier (r14-verified): don't drain vmcnt, so the per-step h2
// global store and ep prefetch loads stay in flight across steps.
__device__ __forceinline__ void lds_barrier() {
    asm volatile("s_waitcnt lgkmcnt(0)" ::: "memory");
    __builtin_amdgcn_s_barrier();
}

#define FMA4F(A, W, H) \
    A = fmaf((W).w, (H).w, fmaf((W).z, (H).z, fmaf((W).y, (H).y, fmaf((W).x, (H).x, A))))

// ---------------------------------------------------------------------------
// Kernel A1 (r20-proven): 8 vocab rows/block; W_ih1 quad loaded once per block
// ---------------------------------------------------------------------------
__global__ __launch_bounds__(128) void emb_proj_kernel(
    const float* __restrict__ emb, const float* __restrict__ W_ih1,
    const float* __restrict__ b_ih1, const float* __restrict__ b_hh1,
    float* __restrict__ emb_proj)
{
    const int v0 = blockIdx.x * 8;
    const int j = threadIdx.x;
    __shared__ __align__(16) float ev[8][DD];

    {
        const float4* esrc = (const float4*)&emb[(long)v0 * DD];
        float4* edst = (float4*)ev;
#pragma unroll
        for (int i = 0; i < 4; ++i) edst[j + 128 * i] = esrc[j + 128 * i];
    }
    __syncthreads();

    const float bias = b_ih1[j] + b_hh1[j];
    float acc[8];
#pragma unroll
    for (int v = 0; v < 8; ++v) acc[v] = bias;

    const float4* wrow = (const float4*)&W_ih1[j * DD];
#pragma unroll 4
    for (int q = 0; q < DD / 4; ++q) {
        const float4 w = wrow[q];
#pragma unroll
        for (int v = 0; v < 8; ++v) {
            const float4 e = ((const float4*)ev[v])[q];
            acc[v] += w.x * e.x + w.y * e.y + w.z * e.z + w.w * e.w;
        }
    }
#pragma unroll
    for (int v = 0; v < 8; ++v)
        emb_proj[(v0 + v) * G4 + j] = acc[v];
}

// ---------------------------------------------------------------------------
// Kernel A2: W_fcT[k][v] = W_fc[v][k]
// ---------------------------------------------------------------------------
__global__ __launch_bounds__(256) void transpose_wfc_kernel(
    const float* __restrict__ W_fc, float* __restrict__ W_fcT)
{
    int i = blockIdx.x * 256 + threadIdx.x;
    int v = i >> 5;
    int k = i & 31;
    W_fcT[k * VV + v] = W_fc[i];
}

// ---------------------------------------------------------------------------
// Kernel B (r20-proven BEST, unchanged): r14 4-wave pipelined LSTM +
// amdgpu_waves_per_eu(1,1). waves 0,1: layer1 step t; waves 2,3: layer2 t-1.
// 481us = ~1120cy/step; residual cost is the 4-wave lockstep barrier
// structure (~600cy/step) -- all structural alternatives measured worse
// (2-wave PC x5, all-LDS weights, balanced homes; r13-r21).
// ---------------------------------------------------------------------------
__global__ __launch_bounds__(256)
__attribute__((amdgpu_waves_per_eu(1, 1)))
void lstm_rec_pipe_kernel(
    const int* __restrict__ x_ids, const float* __restrict__ emb_proj,
    const float* __restrict__ W_hh1, const float* __restrict__ W_ih2,
    const float* __restrict__ W_hh2, const float* __restrict__ b_ih2,
    const float* __restrict__ b_hh2, float* __restrict__ h2_all)
{
    const int tid = threadIdx.x;
    const int b   = blockIdx.x;
    const int wid = tid >> 6;          // 0,1 -> layer1; 2,3 -> layer2
    const int l   = tid & 63;
    const int g   = (l >> 4) & 3;      // gate index
    const int half = l >> 5;
    const int u   = (l & 15) + 16 * (wid & 1);
    const int row = g * 32 + u;

    const float aa = (g == 2) ? 2.0f : 1.0f;   // act: 1 - kk*rcp(1+exp(aa*x))
    const float kk = (g == 2) ? 2.0f : 1.0f;
    const bool is_l1 = (wid < 2);
    const int  gbit0 = g & 1, gbit1 = g >> 1;

    // weights: L1 waves -> w=W_hh1[row]; L2 waves -> w=W_ih2[row], v=W_hh2[row]
    float4 w0,w1,w2,w3,w4,w5,w6,w7, v0,v1,v2,v3,v4,v5,v6,v7;
    {
        const float* wsrc = is_l1 ? W_hh1 : W_ih2;
        const float4* pw = (const float4*)&wsrc[row * HH];
        w0=pw[0]; w1=pw[1]; w2=pw[2]; w3=pw[3];
        w4=pw[4]; w5=pw[5]; w6=pw[6]; w7=pw[7];
        const float4* pv = (const float4*)&W_hh2[row * HH];
        v0=pv[0]; v1=pv[1]; v2=pv[2]; v3=pv[3];
        v4=pv[4]; v5=pv[5]; v6=pv[6]; v7=pv[7];
    }
    const float bias2 = b_ih2[row] + b_hh2[row];

    __shared__ __align__(16) float h1s[2][HH];
    __shared__ __align__(16) float h2s[2][HH];
    if (tid < 64) { h1s[tid >> 5][tid & 31] = 0.0f; h2s[tid >> 5][tid & 31] = 0.0f; }
    __syncthreads();

    float cst = 0.0f;                  // c1 (L1 waves) or c2 (L2 waves)
    const int* ids = x_ids + b * SEQ;
    float ep = 0.0f; int idn = 0;
    if (is_l1) {
        ep  = emb_proj[ids[0] * G4 + row];
        idn = ids[1];
    }
    float* h2out = h2_all + (long)b * SEQ * HH;

    for (int t = 0; t <= SEQ; ++t) {
        const int cur = t & 1, nxt = cur ^ 1;
        if (is_l1) {
            if (t < SEQ) {
                // prefetch ep(t+1) — stays in flight across the counted barrier
                const float epn = emb_proj[idn * G4 + row];
                const int tn2 = (t + 2 < SEQ) ? (t + 2) : (SEQ - 1);
                const int idn2 = ids[tn2];

                // dot: W_hh1[row] . h1(t-1)
                const float4* hv = (const float4*)h1s[cur];
                float a0=0.f, a1=0.f, a2=0.f, a3=0.f;
                float4 q;
                q=hv[0]; FMA4F(a0,w0,q);  q=hv[1]; FMA4F(a1,w1,q);
                q=hv[2]; FMA4F(a2,w2,q);  q=hv[3]; FMA4F(a3,w3,q);
                q=hv[4]; FMA4F(a0,w4,q);  q=hv[5]; FMA4F(a1,w5,q);
                q=hv[6]; FMA4F(a2,w6,q);  q=hv[7]; FMA4F(a3,w7,q);
                const float pre = ep + ((a0 + a1) + (a2 + a3));

                const float A = 1.0f - kk * __builtin_amdgcn_rcpf(1.0f + __expf(aa * pre));
                const float B = lane_xor16(A, l);        // gate g^1
                const float C = lane_xor32(A, half);     // gate g^2
                const float D = lane_xor32(B, half);     // gate g^3
                const float gi = gbit1 ? (gbit0 ? D : C) : (gbit0 ? B : A);
                const float gf = gbit1 ? (gbit0 ? C : D) : (gbit0 ? A : B);
                const float gt = gbit1 ? (gbit0 ? B : A) : (gbit0 ? D : C);
                const float go = gbit1 ? (gbit0 ? A : B) : (gbit0 ? C : D);

                cst = gf * cst + gi * gt;
                const float hn = go * ftanh(cst);
                if (g == 0) h1s[nxt][u] = hn;

                ep = epn; idn = idn2;
            }
        } else {
            if (t >= 1) {
                const int s = t - 1;
                // dots: W_ih2[row].h1(s) and W_hh2[row].h2(s-1)
                const float4* h1v = (const float4*)h1s[cur];
                const float4* h2v = (const float4*)h2s[cur];
                float e0=0.f, e1=0.f, e2=0.f, e3=0.f;
                float p0=0.f, p1=0.f, p2=0.f, p3=0.f;
                float4 q;
                q=h1v[0]; FMA4F(e0,w0,q);  q=h1v[1]; FMA4F(e1,w1,q);
                q=h1v[2]; FMA4F(e2,w2,q);  q=h1v[3]; FMA4F(e3,w3,q);
                q=h1v[4]; FMA4F(e0,w4,q);  q=h1v[5]; FMA4F(e1,w5,q);
                q=h1v[6]; FMA4F(e2,w6,q);  q=h1v[7]; FMA4F(e3,w7,q);
                q=h2v[0]; FMA4F(p0,v0,q);  q=h2v[1]; FMA4F(p1,v1,q);
                q=h2v[2]; FMA4F(p2,v2,q);  q=h2v[3]; FMA4F(p3,v3,q);
                q=h2v[4]; FMA4F(p0,v4,q);  q=h2v[5]; FMA4F(p1,v5,q);
                q=h2v[6]; FMA4F(p2,v6,q);  q=h2v[7]; FMA4F(p3,v7,q);
                const float esum = (e0 + e1) + (e2 + e3);
                const float psum = (p0 + p1) + (p2 + p3);
                const float pre = bias2 + psum + esum;

                const float A = 1.0f - kk * __builtin_amdgcn_rcpf(1.0f + __expf(aa * pre));
                const float B = lane_xor16(A, l);
                const float C = lane_xor32(A, half);
                const float D = lane_xor32(B, half);
                const float gi = gbit1 ? (gbit0 ? D : C) : (gbit0 ? B : A);
                const float gf = gbit1 ? (gbit0 ? C : D) : (gbit0 ? A : B);
                const float gt = gbit1 ? (gbit0 ? B : A) : (gbit0 ? D : C);
                const float go = gbit1 ? (gbit0 ? A : B) : (gbit0 ? C : D);

                cst = gf * cst + gi * gt;
                const float hn = go * ftanh(cst);
                if (g == 0) {
                    h2s[nxt][u] = hn;
                    h2out[(long)s * HH + u] = hn;   // store floats across barrier
                }
            }
        }
        lds_barrier();
    }
}

// ---------------------------------------------------------------------------
// Kernel C (r20-proven): logits = h2 @ W_fc^T + b_fc, row softmax.
// 8 rows/block, 256 threads, 8 vocab cols/thread. Both widenings (16-row/256
// r2, 16-row/512 r22) measured WORSE -- this config stands.
// ---------------------------------------------------------------------------
__global__ __launch_bounds__(256) void fc_softmax_kernel(
    const float* __restrict__ h2_all, const float* __restrict__ W_fcT,
    const float* __restrict__ b_fc, float* __restrict__ out)
{
    const int tid = threadIdx.x;
    const long rowbase = (long)blockIdx.x * 8;
    __shared__ __align__(16) float h2t[8][HH];
    __shared__ float wred[8][4];

    h2t[tid >> 5][tid & 31] = h2_all[rowbase * HH + tid];
    __syncthreads();

    const int v0 = tid * 8;
    const float4 bf0 = *(const float4*)&b_fc[v0];
    const float4 bf1 = *(const float4*)&b_fc[v0 + 4];
    float acc[8][8];
#pragma unroll
    for (int r = 0; r < 8; ++r) {
        acc[r][0] = bf0.x; acc[r][1] = bf0.y; acc[r][2] = bf0.z; acc[r][3] = bf0.w;
        acc[r][4] = bf1.x; acc[r][5] = bf1.y; acc[r][6] = bf1.z; acc[r][7] = bf1.w;
    }

#pragma unroll
    for (int kq = 0; kq < 8; ++kq) {
        const int k = kq * 4;
        float4 wa[4], wb[4];
#pragma unroll
        for (int i = 0; i < 4; ++i) {
            wa[i] = *(const float4*)&W_fcT[(k + i) * VV + v0];
            wb[i] = *(const float4*)&W_fcT[(k + i) * VV + v0 + 4];
        }
#pragma unroll
        for (int r = 0; r < 8; ++r) {
            const float4 h = *(const float4*)&h2t[r][k];
            const float hh[4] = {h.x, h.y, h.z, h.w};
#pragma unroll
            for (int i = 0; i < 4; ++i) {
                acc[r][0] += hh[i] * wa[i].x; acc[r][1] += hh[i] * wa[i].y;
                acc[r][2] += hh[i] * wa[i].z; acc[r][3] += hh[i] * wa[i].w;
                acc[r][4] += hh[i] * wb[i].x; acc[r][5] += hh[i] * wb[i].y;
                acc[r][6] += hh[i] * wb[i].z; acc[r][7] += hh[i] * wb[i].w;
            }
        }
    }

    const int wv = tid >> 6;
    const int lane = tid & 63;

    float m[8];
#pragma unroll
    for (int r = 0; r < 8; ++r) {
        float v = acc[r][0];
#pragma unroll
        for (int c = 1; c < 8; ++c) v = fmaxf(v, acc[r][c]);
#pragma unroll
        for (int s = 32; s >= 1; s >>= 1) v = fmaxf(v, __shfl_xor(v, s, 64));
        m[r] = v;
    }
    if (lane == 0) {
#pragma unroll
        for (int r = 0; r < 8; ++r) wred[r][wv] = m[r];
    }
    __syncthreads();
    float rm[8];
#pragma unroll
    for (int r = 0; r < 8; ++r)
        rm[r] = fmaxf(fmaxf(wred[r][0], wred[r][1]), fmaxf(wred[r][2], wred[r][3]));
    __syncthreads();

    float s[8];
#pragma unroll
    for (int r = 0; r < 8; ++r) {
        float sum = 0.0f;
#pragma unroll
        for (int c = 0; c < 8; ++c) {
            float e = __expf(acc[r][c] - rm[r]);
            acc[r][c] = e;
            sum += e;
        }
#pragma unroll
        for (int st = 32; st >= 1; st >>= 1) sum += __shfl_xor(sum, st, 64);
        s[r] = sum;
    }
    if (lane == 0) {
#pragma unroll
        for (int r = 0; r < 8; ++r) wred[r][wv] = s[r];
    }
    __syncthreads();

#pragma unroll
    for (int r = 0; r < 8; ++r) {
        const float rs = wred[r][0] + wred[r][1] + wred[r][2] + wred[r][3];
        const float inv = 1.0f / rs;
        float4 o0 = make_float4(acc[r][0] * inv, acc[r][1] * inv, acc[r][2] * inv, acc[r][3] * inv);
        float4 o1 = make_float4(acc[r][4] * inv, acc[r][5] * inv, acc[r][6] * inv, acc[r][7] * inv);
        float* op = out + (rowbase + r) * VV + v0;
        *(float4*)op = o0;
        *(float4*)(op + 4) = o1;
    }
}

// ---------------------------------------------------------------------------
extern "C" void kernel_launch(void* const* d_in, const int* in_sizes, int n_in,
                              void* d_out, int out_size, void* d_ws, size_t ws_size,
                              hipStream_t stream)
{
    const int*   x_ids = (const int*)d_in[0];
    const float* emb   = (const float*)d_in[1];
    const float* W_ih1 = (const float*)d_in[2];
    const float* W_hh1 = (const float*)d_in[3];
    const float* b_ih1 = (const float*)d_in[4];
    const float* b_hh1 = (const float*)d_in[5];
    const float* W_ih2 = (const float*)d_in[6];
    const float* W_hh2 = (const float*)d_in[7];
    const float* b_ih2 = (const float*)d_in[8];
    const float* b_hh2 = (const float*)d_in[9];
    const float* W_fc  = (const float*)d_in[10];
    const float* b_fc  = (const float*)d_in[11];
    float* out = (float*)d_out;

    float* ws = (float*)d_ws;
    float* emb_proj = ws;                         // V*4H   = 262144
    float* W_fcT    = ws + 262144;                // H*V    = 65536
    float* h2_all   = ws + 262144 + 65536;        // B*S*H  = 2097152

    emb_proj_kernel<<<VV / 8, 128, 0, stream>>>(emb, W_ih1, b_ih1, b_hh1, emb_proj);
    transpose_wfc_kernel<<<(VV * HH) / 256, 256, 0, stream>>>(W_fc, W_fcT);
    lstm_rec_pipe_kernel<<<BB, 256, 0, stream>>>(x_ids, emb_proj, W_hh1, W_ih2, W_hh2,
                                                 b_ih2, b_hh2, h2_all);
    fc_softmax_kernel<<<(BB * SEQ) / 8, 256, 0, stream>>>(h2_all, W_fcT, b_fc, out);
}